// Round 1
// baseline (18702.165 us; speedup 1.0000x reference)
//
#include <hip/hip_runtime.h>
#include <hip/hip_cooperative_groups.h>
#include <cstdint>
#include <cstddef>

namespace cg = cooperative_groups;

// Problem constants (fixed by the reference)
#define NB 32      // batch
#define NT 1024    // timesteps
#define ND 512     // input dim (== hidden)
#define NH 512     // hidden
#define NG 2048    // 4*H gate width
#define SEQELEMS ((size_t)NB * NT * NH)   // 16,777,216

typedef __attribute__((ext_vector_type(8))) short bf16x8;
typedef __attribute__((ext_vector_type(4))) float f32x4;

__device__ __forceinline__ unsigned short f2bf(float f) {
    union { float f; unsigned u; } v; v.f = f;
    unsigned r = v.u + 0x7fffu + ((v.u >> 16) & 1u);   // RNE
    return (unsigned short)(r >> 16);
}
__device__ __forceinline__ float sigf(float x)  { return 1.f / (1.f + __expf(-x)); }
__device__ __forceinline__ float tanhf_(float x){ return 1.f - 2.f / (1.f + __expf(2.f * x)); }

// ---------------- prologue: fp32 -> bf16 convert of x ----------------
__global__ void cvt_bf16_kernel(const float* __restrict__ src,
                                unsigned short* __restrict__ dst, int n4) {
    int i = blockIdx.x * blockDim.x + threadIdx.x;
    if (i < n4) {
        float4 v = ((const float4*)src)[i];
        ushort4 o;
        o.x = f2bf(v.x); o.y = f2bf(v.y); o.z = f2bf(v.z); o.w = f2bf(v.w);
        ((ushort4*)dst)[i] = o;
    }
}

// ---------------- main cooperative LSTM kernel ----------------
// Grid: 128 blocks x 512 threads. blocks [0,64): layer 0, [64,128): layer 1.
// Block owns 8 hidden columns (j0..j0+7) => 32 gate columns (f,g,i,o x 8).
// Wavefront pipeline: global step s -> layer l computes t = s - l.
// Per step: gates[32 x 32] = XH[32 x 1024]_bf16 @ W[1024 x 32]_bf16 + bias,
// XH = [x_t | h_{t-1}] read from global bf16 history; W stationary in VGPRs.
__launch_bounds__(512, 1)
__global__ void lstm_coop(const unsigned short* __restrict__ xb,   // [B][T][512] bf16
                          unsigned short* __restrict__ ys,         // [2][B][T][512] bf16 history
                          const float* __restrict__ Wx,            // [2][512][2048]
                          const float* __restrict__ bx,            // [2][2048]
                          const float* __restrict__ Wh,            // [2][512][2048]
                          const float* __restrict__ bh,            // [2][2048]
                          float* __restrict__ out)                 // seq | h | c
{
    __shared__ __align__(16) unsigned short Wp[2][16][1032];  // [ntile][n][k] padded (+8)
    __shared__ float part[8][32][33];                         // K-split partials (padded)
    __shared__ float gbuf[32][33];                            // reduced gates
    __shared__ float cst[32][8];                              // cell state (block-local!)
    __shared__ float biasv[32];

    const int tid   = threadIdx.x;
    const int bid   = blockIdx.x;
    const int layer = bid >> 6;       // 0 or 1
    const int cgp   = bid & 63;       // column group
    const int j0    = cgp * 8;        // first hidden column of this block

    // ---- stage this block's weight slice into LDS as W^T bf16 ----
    // n = gate*8 + jj  (gate order f,g,i,o), actual gate col = gate*512 + j0 + jj
    for (int idx = tid; idx < 32 * 1024; idx += 512) {
        int n = idx >> 10;          // 0..31
        int k = idx & 1023;         // 0..1023
        int gate = n >> 3;
        int col  = gate * 512 + j0 + (n & 7);
        float w = (k < 512)
            ? Wx[(size_t)layer * 512 * NG + (size_t)k * NG + col]
            : Wh[(size_t)layer * 512 * NG + (size_t)(k - 512) * NG + col];
        Wp[n >> 4][n & 15][k] = f2bf(w);
    }
    if (tid < 32) {
        int gate = tid >> 3;
        int col  = gate * 512 + j0 + (tid & 7);
        biasv[tid] = bx[layer * NG + col] + bh[layer * NG + col];
    }
    if (tid < 256) cst[tid >> 3][tid & 7] = 0.f;
    __syncthreads();

    const unsigned short* seqin = (layer == 0) ? xb : ys;          // input sequence
    const unsigned short* hist  = ys + (size_t)layer * SEQELEMS;   // own h history
    unsigned short*       ysl   = ys + (size_t)layer * SEQELEMS;

    const int wid  = tid >> 6;        // wave id 0..7 == K-slice id
    const int lane = tid & 63;
    const int kh   = wid;             // K-slice of 128
    const int kb   = kh << 7;
    const int q    = lane >> 4;       // quad
    const int ln   = lane & 15;

    // ---- preload B fragments (weights) into registers: stationary across t ----
    bf16x8 breg0[4], breg1[4];
    #pragma unroll
    for (int ks = 0; ks < 4; ++ks) {
        int klane = kb + ks * 32 + q * 8;
        breg0[ks] = *(const bf16x8*)&Wp[0][ln][klane];
        breg1[ks] = *(const bf16x8*)&Wp[1][ln][klane];
    }

    const size_t mstride = (size_t)16 * NT * 512;  // batch +16 offset in elements
    cg::grid_group grid = cg::this_grid();

    for (int s = 0; s < NT + 1; ++s) {
        const int t = s - layer;
        const bool active = (t >= 0) && (t < NT);

        if (active) {
            f32x4 acc00 = {0,0,0,0}, acc01 = {0,0,0,0};
            f32x4 acc10 = {0,0,0,0}, acc11 = {0,0,0,0};
            #pragma unroll
            for (int ks = 0; ks < 4; ++ks) {
                const int kk    = kb + ks * 32;
                const int klane = kk + q * 8;
                bf16x8 a0, a1;
                if (kk < 512) {                       // x-part (wave-uniform branch)
                    const size_t base = ((size_t)ln * NT + t) * 512 + klane;
                    a0 = *(const bf16x8*)(seqin + base);
                    a1 = *(const bf16x8*)(seqin + base + mstride);
                } else if (t > 0) {                   // h-part
                    const size_t base = ((size_t)ln * NT + (t - 1)) * 512 + (klane - 512);
                    a0 = *(const bf16x8*)(hist + base);
                    a1 = *(const bf16x8*)(hist + base + mstride);
                } else {
                    a0 = bf16x8{0,0,0,0,0,0,0,0};
                    a1 = bf16x8{0,0,0,0,0,0,0,0};
                }
                acc00 = __builtin_amdgcn_mfma_f32_16x16x32_bf16(a0, breg0[ks], acc00, 0,0,0);
                acc10 = __builtin_amdgcn_mfma_f32_16x16x32_bf16(a1, breg0[ks], acc10, 0,0,0);
                acc01 = __builtin_amdgcn_mfma_f32_16x16x32_bf16(a0, breg1[ks], acc01, 0,0,0);
                acc11 = __builtin_amdgcn_mfma_f32_16x16x32_bf16(a1, breg1[ks], acc11, 0,0,0);
            }
            // C/D layout (m89): col = lane&15, row = quad*4 + r
            #pragma unroll
            for (int r = 0; r < 4; ++r) {
                part[kh][     q*4 + r][     ln] = acc00[r];
                part[kh][16 + q*4 + r][     ln] = acc10[r];
                part[kh][     q*4 + r][16 + ln] = acc01[r];
                part[kh][16 + q*4 + r][16 + ln] = acc11[r];
            }
        }
        __syncthreads();

        if (active) {
            // K-split reduction + bias
            for (int idx = tid; idx < 32 * 32; idx += 512) {
                int m = idx >> 5, n = idx & 31;
                float v = biasv[n];
                #pragma unroll
                for (int k8 = 0; k8 < 8; ++k8) v += part[k8][m][n];
                gbuf[m][n] = v;
            }
        }
        __syncthreads();

        if (active && tid < 256) {
            const int m = tid >> 3, jj = tid & 7;
            float f = sigf (gbuf[m][jj]);
            float g = tanhf_(gbuf[m][ 8 + jj]);
            float i = sigf (gbuf[m][16 + jj]);
            float o = sigf (gbuf[m][24 + jj]);
            float c = f * cst[m][jj] + i * g;
            cst[m][jj] = c;
            float h = o * tanhf_(c);
            const size_t oidx = ((size_t)m * NT + t) * 512 + j0 + jj;
            ysl[oidx] = f2bf(h);                       // bf16 history for next step / layer 2
            if (layer == 1) out[oidx] = h;             // final sequence output (fp32)
            if (t == NT - 1) {                         // final h, c -> [B][L][H]
                const size_t hoff = SEQELEMS + ((size_t)m * 2 + layer) * 512 + j0 + jj;
                out[hoff] = h;
                out[hoff + (size_t)NB * 2 * 512] = c;
            }
        }
        grid.sync();
    }
}

extern "C" void kernel_launch(void* const* d_in, const int* in_sizes, int n_in,
                              void* d_out, int out_size, void* d_ws, size_t ws_size,
                              hipStream_t stream) {
    const float* x  = (const float*)d_in[0];
    const float* Wx = (const float*)d_in[1];
    const float* bx = (const float*)d_in[2];
    const float* Wh = (const float*)d_in[3];
    const float* bh = (const float*)d_in[4];
    float* out = (float*)d_out;

    // workspace layout: x_bf16 [B][T][512] | ys_bf16 [2][B][T][512]  (~100.7 MB)
    unsigned short* xb = (unsigned short*)d_ws;
    unsigned short* ys = xb + SEQELEMS;

    int n4 = (int)(SEQELEMS / 4);
    cvt_bf16_kernel<<<dim3((n4 + 255) / 256), dim3(256), 0, stream>>>(x, xb, n4);

    void* args[] = { (void*)&xb, (void*)&ys, (void*)&Wx, (void*)&bx,
                     (void*)&Wh, (void*)&bh, (void*)&out };
    hipLaunchCooperativeKernel((void*)lstm_coop, dim3(128), dim3(512), args, 0, stream);
}

// Round 2
// 7420.732 us; speedup vs baseline: 2.5203x; 2.5203x over previous
//
#include <hip/hip_runtime.h>
#include <cstdint>
#include <cstddef>

// Problem constants (fixed by the reference)
#define NB 32      // batch
#define NT 1024    // timesteps
#define ND 512     // input dim (== hidden)
#define NH 512     // hidden
#define NG 2048    // 4*H gate width
#define SEQELEMS ((size_t)NB * NT * NH)   // 16,777,216

typedef __attribute__((ext_vector_type(8))) short bf16x8;
typedef __attribute__((ext_vector_type(4))) float f32x4;

__device__ __forceinline__ unsigned short f2bf(float f) {
    union { float f; unsigned u; } v; v.f = f;
    unsigned r = v.u + 0x7fffu + ((v.u >> 16) & 1u);   // RNE
    return (unsigned short)(r >> 16);
}
__device__ __forceinline__ float sigf(float x)  { return 1.f / (1.f + __expf(-x)); }
__device__ __forceinline__ float tanhf_(float x){ return 1.f - 2.f / (1.f + __expf(2.f * x)); }

// system-scope (sc0 sc1) cache-bypassing 16B load as two 8B relaxed atomics
__device__ __forceinline__ bf16x8 ld_sys16(const unsigned short* p) {
    union { bf16x8 v; unsigned long long q[2]; } u;
    u.q[0] = __hip_atomic_load((const unsigned long long*)p,
                               __ATOMIC_RELAXED, __HIP_MEMORY_SCOPE_SYSTEM);
    u.q[1] = __hip_atomic_load((const unsigned long long*)p + 1,
                               __ATOMIC_RELAXED, __HIP_MEMORY_SCOPE_SYSTEM);
    return u.v;
}

// all 64 lanes of the calling wave poll one flag each until all >= need
__device__ __forceinline__ void wait_flags(const int* fl, int need, int lane) {
    int v = __hip_atomic_load(fl + lane, __ATOMIC_RELAXED, __HIP_MEMORY_SCOPE_SYSTEM);
    while (__ballot(v >= need) != ~0ull) {
        __builtin_amdgcn_s_sleep(1);
        v = __hip_atomic_load(fl + lane, __ATOMIC_RELAXED, __HIP_MEMORY_SCOPE_SYSTEM);
    }
    asm volatile("" ::: "memory");   // compiler: no hoisting of data loads above poll
}

// ---------------- prologue: fp32 -> bf16 convert of x ----------------
__global__ void cvt_bf16_kernel(const float* __restrict__ src,
                                unsigned short* __restrict__ dst, int n4) {
    int i = blockIdx.x * blockDim.x + threadIdx.x;
    if (i < n4) {
        float4 v = ((const float4*)src)[i];
        ushort4 o;
        o.x = f2bf(v.x); o.y = f2bf(v.y); o.z = f2bf(v.z); o.w = f2bf(v.w);
        ((ushort4*)dst)[i] = o;
    }
}

// ---------------- main self-timed LSTM kernel ----------------
// 128 blocks x 512 threads; blocks [0,64): layer 0, [64,128): layer 1.
// Block owns 8 hidden columns => 32 gate columns; weights stationary in VGPRs.
// No grid barrier: per-block flags + system-scope (coherence-point) data path.
__launch_bounds__(512, 1)
__global__ void lstm_selftimed(const unsigned short* __restrict__ xb, // [B][T][512] bf16
                               unsigned short* __restrict__ ys,       // [2][B][T][512] bf16
                               int* __restrict__ flags,               // [2][64]
                               const float* __restrict__ Wx,          // [2][512][2048]
                               const float* __restrict__ bx,          // [2][2048]
                               const float* __restrict__ Wh,          // [2][512][2048]
                               const float* __restrict__ bh,          // [2][2048]
                               float* __restrict__ out)               // seq | h | c
{
    __shared__ __align__(16) unsigned short Wp[2][16][1032];  // staging (+8 pad)
    __shared__ float part[8][32][36];   // K-split partials; pad 36 -> <=2-way conflicts
    __shared__ float cst[32][8];        // cell state (block-local)
    __shared__ __align__(8) unsigned short hbuf[32][8];  // h slice staging (bf16)
    __shared__ float biasv[32];

    const int tid   = threadIdx.x;
    const int bid   = blockIdx.x;
    const int layer = bid >> 6;
    const int cgp   = bid & 63;
    const int j0    = cgp * 8;

    // ---- stage this block's weight slice into LDS as W^T bf16 ----
    for (int idx = tid; idx < 32 * 1024; idx += 512) {
        int n = idx >> 10;          // 0..31 (gate*8 + jj)
        int k = idx & 1023;
        int gate = n >> 3;
        int col  = gate * 512 + j0 + (n & 7);
        float w = (k < 512)
            ? Wx[(size_t)layer * 512 * NG + (size_t)k * NG + col]
            : Wh[(size_t)layer * 512 * NG + (size_t)(k - 512) * NG + col];
        Wp[n >> 4][n & 15][k] = f2bf(w);
    }
    if (tid < 32) {
        int gate = tid >> 3;
        int col  = gate * 512 + j0 + (tid & 7);
        biasv[tid] = bx[layer * NG + col] + bh[layer * NG + col];
    }
    if (tid < 256) cst[tid >> 3][tid & 7] = 0.f;
    __syncthreads();

    const unsigned short* ys0  = ys;                               // layer-0 output
    const unsigned short* hist = ys + (size_t)layer * SEQELEMS;    // own h history
    unsigned short*       ysl  = ys + (size_t)layer * SEQELEMS;
    int* myflag = flags + layer * 64 + cgp;
    const int* ownfl = flags + layer * 64;   // same-layer flags
    const int* l0fl  = flags;                // layer-0 flags

    const int wid  = tid >> 6;        // wave id == K-slice (128 wide)
    const int lane = tid & 63;
    const int kb   = wid << 7;
    const int q    = lane >> 4;
    const int ln   = lane & 15;
    const bool hwave = (wid >= 4);    // K-slices 512..1023 = h part

    // ---- preload B fragments (weights) into registers ----
    bf16x8 breg0[4], breg1[4];
    #pragma unroll
    for (int ks = 0; ks < 4; ++ks) {
        int klane = kb + ks * 32 + q * 8;
        breg0[ks] = *(const bf16x8*)&Wp[0][ln][klane];
        breg1[ks] = *(const bf16x8*)&Wp[1][ln][klane];
    }

    const size_t mstride = (size_t)16 * NT * 512;

    for (int t = 0; t < NT; ++t) {
        // ---- phase A: wait deps, load A-frags, MFMA, write partials ----
        if (layer == 1 && !hwave) wait_flags(l0fl, t, lane);        // need ys0(t)
        if (hwave && t > 0)       wait_flags(ownfl, t - 1, lane);   // need own h(t-1)

        f32x4 acc00 = {0,0,0,0}, acc01 = {0,0,0,0};
        f32x4 acc10 = {0,0,0,0}, acc11 = {0,0,0,0};
        #pragma unroll
        for (int ks = 0; ks < 4; ++ks) {
            const int klane = kb + ks * 32 + q * 8;
            bf16x8 a0, a1;
            if (!hwave) {
                const size_t base = ((size_t)ln * NT + t) * 512 + klane;
                if (layer == 0) {
                    a0 = *(const bf16x8*)(xb + base);
                    a1 = *(const bf16x8*)(xb + base + mstride);
                } else {
                    a0 = ld_sys16(ys0 + base);
                    a1 = ld_sys16(ys0 + base + mstride);
                }
            } else if (t > 0) {
                const size_t base = ((size_t)ln * NT + (t - 1)) * 512 + (klane - 512);
                a0 = ld_sys16(hist + base);
                a1 = ld_sys16(hist + base + mstride);
            } else {
                a0 = bf16x8{0,0,0,0,0,0,0,0};
                a1 = bf16x8{0,0,0,0,0,0,0,0};
            }
            acc00 = __builtin_amdgcn_mfma_f32_16x16x32_bf16(a0, breg0[ks], acc00, 0,0,0);
            acc10 = __builtin_amdgcn_mfma_f32_16x16x32_bf16(a1, breg0[ks], acc10, 0,0,0);
            acc01 = __builtin_amdgcn_mfma_f32_16x16x32_bf16(a0, breg1[ks], acc01, 0,0,0);
            acc11 = __builtin_amdgcn_mfma_f32_16x16x32_bf16(a1, breg1[ks], acc11, 0,0,0);
        }
        #pragma unroll
        for (int r = 0; r < 4; ++r) {   // C/D: col=lane&15, row=quad*4+r (m89)
            part[wid][     q*4 + r][     ln] = acc00[r];
            part[wid][16 + q*4 + r][     ln] = acc10[r];
            part[wid][     q*4 + r][16 + ln] = acc01[r];
            part[wid][16 + q*4 + r][16 + ln] = acc11[r];
        }
        __syncthreads();   // S1

        // ---- phase B: reduce + gates + state update (fused, 256 threads) ----
        if (tid < 256) {
            const int m = tid >> 3, jj = tid & 7;
            float gv[4];
            #pragma unroll
            for (int g = 0; g < 4; ++g) {
                float v = biasv[g * 8 + jj];
                #pragma unroll
                for (int k8 = 0; k8 < 8; ++k8) v += part[k8][m][g * 8 + jj];
                gv[g] = v;
            }
            float f = sigf(gv[0]);
            float g = tanhf_(gv[1]);
            float i = sigf(gv[2]);
            float o = sigf(gv[3]);
            float c = f * cst[m][jj] + i * g;
            cst[m][jj] = c;
            float h = o * tanhf_(c);
            hbuf[m][jj] = f2bf(h);
            const size_t oidx = ((size_t)m * NT + t) * 512 + j0 + jj;
            if (layer == 1) out[oidx] = h;
            if (t == NT - 1) {
                const size_t hoff = SEQELEMS + ((size_t)m * 2 + layer) * 512 + j0 + jj;
                out[hoff] = h;
                out[hoff + (size_t)NB * 2 * 512] = c;
            }
        }
        __syncthreads();   // S2

        // ---- phase C: publish h slice (wave 0 only) + flag ----
        if (tid < 64) {
            const int m = tid >> 1, half = tid & 1;
            unsigned long long qv = ((const unsigned long long*)hbuf)[tid];
            const size_t off = ((size_t)m * NT + t) * 512 + j0 + half * 4;
            __hip_atomic_store((unsigned long long*)(ysl + off), qv,
                               __ATOMIC_RELAXED, __HIP_MEMORY_SCOPE_SYSTEM);
            if (tid == 0) {
                asm volatile("s_waitcnt vmcnt(0)" ::: "memory");  // stores acked at coherence pt
                __hip_atomic_store(myflag, t, __ATOMIC_RELAXED, __HIP_MEMORY_SCOPE_SYSTEM);
            }
        }
        // no further sync needed: next round's LDS writes are fenced by S1/S2 per wave
    }
}

extern "C" void kernel_launch(void* const* d_in, const int* in_sizes, int n_in,
                              void* d_out, int out_size, void* d_ws, size_t ws_size,
                              hipStream_t stream) {
    const float* x  = (const float*)d_in[0];
    const float* Wx = (const float*)d_in[1];
    const float* bx = (const float*)d_in[2];
    const float* Wh = (const float*)d_in[3];
    const float* bh = (const float*)d_in[4];
    float* out = (float*)d_out;

    // workspace: x_bf16 [B][T][512] | ys_bf16 [2][B][T][512] | flags[128]
    unsigned short* xb = (unsigned short*)d_ws;
    unsigned short* ys = xb + SEQELEMS;
    int* flags = (int*)(ys + 2 * SEQELEMS);
    // flags are poisoned to 0xAAAAAAAA (<0) by the harness each launch; producers
    // only ever store t >= 0, so polls (need >= 0) correctly wait on poison.

    int n4 = (int)(SEQELEMS / 4);
    cvt_bf16_kernel<<<dim3((n4 + 255) / 256), dim3(256), 0, stream>>>(x, xb, n4);

    void* args[] = { (void*)&xb, (void*)&ys, (void*)&flags, (void*)&Wx, (void*)&bx,
                     (void*)&Wh, (void*)&bh, (void*)&out };
    hipLaunchCooperativeKernel((void*)lstm_selftimed, dim3(128), dim3(512), args, 0, stream);
}

// Round 5
// 7195.355 us; speedup vs baseline: 2.5992x; 1.0313x over previous
//
#include <hip/hip_runtime.h>
#include <cstdint>
#include <cstddef>

// Problem constants (fixed by the reference)
#define NB 32      // batch
#define NT 1024    // timesteps
#define ND 512     // input dim (== hidden)
#define NH 512     // hidden
#define NG 2048    // 4*H gate width
#define SEQELEMS ((size_t)NB * NT * NH)   // 16,777,216

typedef __attribute__((ext_vector_type(8))) short bf16x8;
typedef __attribute__((ext_vector_type(4))) float f32x4;

__device__ __forceinline__ unsigned short f2bf(float f) {
    union { float f; unsigned u; } v; v.f = f;
    unsigned r = v.u + 0x7fffu + ((v.u >> 16) & 1u);   // RNE
    return (unsigned short)(r >> 16);
}
__device__ __forceinline__ float sigf(float x)  { return 1.f / (1.f + __expf(-x)); }
__device__ __forceinline__ float tanhf_(float x){ return 1.f - 2.f / (1.f + __expf(2.f * x)); }

// system-scope (sc0 sc1) cache-bypassing 16B load as two 8B relaxed atomics
__device__ __forceinline__ bf16x8 ld_sys16(const unsigned short* p) {
    union { bf16x8 v; unsigned long long q[2]; } u;
    u.q[0] = __hip_atomic_load((const unsigned long long*)p,
                               __ATOMIC_RELAXED, __HIP_MEMORY_SCOPE_SYSTEM);
    u.q[1] = __hip_atomic_load((const unsigned long long*)p + 1,
                               __ATOMIC_RELAXED, __HIP_MEMORY_SCOPE_SYSTEM);
    return u.v;
}

// ---------------- prologue: fp32 -> bf16 convert of x ----------------
__global__ void cvt_bf16_kernel(const float* __restrict__ src,
                                unsigned short* __restrict__ dst, int n4) {
    int i = blockIdx.x * blockDim.x + threadIdx.x;
    if (i < n4) {
        float4 v = ((const float4*)src)[i];
        ushort4 o;
        o.x = f2bf(v.x); o.y = f2bf(v.y); o.z = f2bf(v.z); o.w = f2bf(v.w);
        ((ushort4*)dst)[i] = o;
    }
}

// ---------------- main self-timed LSTM kernel ----------------
// EXACT R2 structure (proven pass @7.4ms) with ONE change: centralized polling.
// 128 blocks x 512 threads; blocks [0,64): layer 0, [64,128): layer 1.
// Block owns 8 hidden columns => 32 gate columns; weights stationary in VGPRs.
// Wave 7 polls all dependency flags, S0 __syncthreads releases the block
// (R2 had 4-8 polling waves per block -> coherence-point poll storm).
__launch_bounds__(512, 1)
__global__ void lstm_v5(const unsigned short* __restrict__ xb,  // [B][T][512] bf16
                        unsigned short* __restrict__ ys,        // [2][B][T][512] bf16
                        int* __restrict__ flags,                // [2][64] dense (R2 slot)
                        const float* __restrict__ Wx,           // [2][512][2048]
                        const float* __restrict__ bx,           // [2][2048]
                        const float* __restrict__ Wh,           // [2][512][2048]
                        const float* __restrict__ bh,           // [2][2048]
                        float* __restrict__ out)                // seq | h | c
{
    __shared__ __align__(16) unsigned short Wp[2][16][1032];  // staging (+8 pad)
    __shared__ float part[8][32][36];   // K-split partials
    __shared__ float cst[32][8];        // cell state (block-local)
    __shared__ __align__(8) unsigned short hbuf[32][8];
    __shared__ float biasv[32];

    const int tid   = threadIdx.x;
    const int bid   = blockIdx.x;
    const int layer = bid >> 6;
    const int cgp   = bid & 63;
    const int j0    = cgp * 8;

    // ---- stage this block's weight slice into LDS as W^T bf16 ----
    for (int idx = tid; idx < 32 * 1024; idx += 512) {
        int n = idx >> 10;          // 0..31 (gate*8 + jj)
        int k = idx & 1023;
        int gate = n >> 3;
        int col  = gate * 512 + j0 + (n & 7);
        float w = (k < 512)
            ? Wx[(size_t)layer * 512 * NG + (size_t)k * NG + col]
            : Wh[(size_t)layer * 512 * NG + (size_t)(k - 512) * NG + col];
        Wp[n >> 4][n & 15][k] = f2bf(w);
    }
    if (tid < 32) {
        int gate = tid >> 3;
        int col  = gate * 512 + j0 + (tid & 7);
        biasv[tid] = bx[layer * NG + col] + bh[layer * NG + col];
    }
    if (tid < 256) cst[tid >> 3][tid & 7] = 0.f;
    __syncthreads();

    const unsigned short* ys0  = ys;                               // layer-0 output
    const unsigned short* hist = ys + (size_t)layer * SEQELEMS;    // own h history
    unsigned short*       ysl  = ys + (size_t)layer * SEQELEMS;
    int* myflag = flags + layer * 64 + cgp;
    const int* ownfl = flags + layer * 64;   // same-layer flags
    const int* l0fl  = flags;                // layer-0 flags

    const int wid  = tid >> 6;        // wave id == K-slice (128 wide)
    const int lane = tid & 63;
    const int kb   = wid << 7;
    const int q    = lane >> 4;
    const int ln   = lane & 15;
    const bool hwave = (wid >= 4);    // K-slices 512..1023 = h part

    // ---- preload B fragments (weights) into registers ----
    bf16x8 breg0[4], breg1[4];
    #pragma unroll
    for (int ks = 0; ks < 4; ++ks) {
        int klane = kb + ks * 32 + q * 8;
        breg0[ks] = *(const bf16x8*)&Wp[0][ln][klane];
        breg1[ks] = *(const bf16x8*)&Wp[1][ln][klane];
    }

    const size_t mstride = (size_t)16 * NT * 512;

    for (int t = 0; t < NT; ++t) {
        // ---- S0: single-wave poll of ALL dependencies, then release block ----
        if (wid == 7) {
            const bool nOwn = (t > 0);        // need own-layer h(t-1)
            const bool nL0  = (layer == 1);   // need layer-0 y(t)
            for (;;) {
                int v1 = nOwn ? __hip_atomic_load(ownfl + lane, __ATOMIC_RELAXED,
                                                  __HIP_MEMORY_SCOPE_SYSTEM)
                              : 0x7fffffff;
                int v2 = nL0  ? __hip_atomic_load(l0fl + lane, __ATOMIC_RELAXED,
                                                  __HIP_MEMORY_SCOPE_SYSTEM)
                              : 0x7fffffff;
                bool ok = (__ballot(v1 >= t - 1) == ~0ull) &&
                          (__ballot(v2 >= t)     == ~0ull);
                if (ok) break;
                __builtin_amdgcn_s_sleep(1);
            }
            asm volatile("" ::: "memory");   // no hoisting data loads above poll
        }
        __syncthreads();   // S0

        // ---- phase A: A-frag loads + MFMA ----
        f32x4 acc00 = {0,0,0,0}, acc01 = {0,0,0,0};
        f32x4 acc10 = {0,0,0,0}, acc11 = {0,0,0,0};
        #pragma unroll
        for (int ks = 0; ks < 4; ++ks) {
            const int klane = kb + ks * 32 + q * 8;
            bf16x8 a0, a1;
            if (!hwave) {
                const size_t base = ((size_t)ln * NT + t) * 512 + klane;
                if (layer == 0) {
                    a0 = *(const bf16x8*)(xb + base);
                    a1 = *(const bf16x8*)(xb + base + mstride);
                } else {
                    a0 = ld_sys16(ys0 + base);
                    a1 = ld_sys16(ys0 + base + mstride);
                }
            } else if (t > 0) {
                const size_t base = ((size_t)ln * NT + (t - 1)) * 512 + (klane - 512);
                a0 = ld_sys16(hist + base);
                a1 = ld_sys16(hist + base + mstride);
            } else {
                a0 = bf16x8{0,0,0,0,0,0,0,0};
                a1 = bf16x8{0,0,0,0,0,0,0,0};
            }
            acc00 = __builtin_amdgcn_mfma_f32_16x16x32_bf16(a0, breg0[ks], acc00, 0,0,0);
            acc10 = __builtin_amdgcn_mfma_f32_16x16x32_bf16(a1, breg0[ks], acc10, 0,0,0);
            acc01 = __builtin_amdgcn_mfma_f32_16x16x32_bf16(a0, breg1[ks], acc01, 0,0,0);
            acc11 = __builtin_amdgcn_mfma_f32_16x16x32_bf16(a1, breg1[ks], acc11, 0,0,0);
        }
        #pragma unroll
        for (int r = 0; r < 4; ++r) {   // C/D: col=lane&15, row=quad*4+r (m89)
            part[wid][     q*4 + r][     ln] = acc00[r];
            part[wid][16 + q*4 + r][     ln] = acc10[r];
            part[wid][     q*4 + r][16 + ln] = acc01[r];
            part[wid][16 + q*4 + r][16 + ln] = acc11[r];
        }
        __syncthreads();   // S1

        // ---- phase B: reduce + gates + state update (fused, 256 threads) ----
        if (tid < 256) {
            const int m = tid >> 3, jj = tid & 7;
            float gv[4];
            #pragma unroll
            for (int g = 0; g < 4; ++g) {
                float v = biasv[g * 8 + jj];
                #pragma unroll
                for (int k8 = 0; k8 < 8; ++k8) v += part[k8][m][g * 8 + jj];
                gv[g] = v;
            }
            float f = sigf(gv[0]);
            float g = tanhf_(gv[1]);
            float i = sigf(gv[2]);
            float o = sigf(gv[3]);
            float c = f * cst[m][jj] + i * g;
            cst[m][jj] = c;
            float h = o * tanhf_(c);
            hbuf[m][jj] = f2bf(h);
            const size_t oidx = ((size_t)m * NT + t) * 512 + j0 + jj;
            if (layer == 1) out[oidx] = h;
            if (t == NT - 1) {
                const size_t hoff = SEQELEMS + ((size_t)m * 2 + layer) * 512 + j0 + jj;
                out[hoff] = h;
                out[hoff + (size_t)NB * 2 * 512] = c;
            }
        }
        __syncthreads();   // S2

        // ---- phase C: publish h slice (wave 0) + post flag ----
        if (tid < 64) {
            const int m = tid >> 1, half = tid & 1;
            unsigned long long qv = ((const unsigned long long*)hbuf)[tid];
            const size_t off = ((size_t)m * NT + t) * 512 + j0 + half * 4;
            __hip_atomic_store((unsigned long long*)(ysl + off), qv,
                               __ATOMIC_RELAXED, __HIP_MEMORY_SCOPE_SYSTEM);
            if (tid == 0) {
                asm volatile("s_waitcnt vmcnt(0)" ::: "memory");  // data at coherence pt
                __hip_atomic_store(myflag, t, __ATOMIC_RELAXED, __HIP_MEMORY_SCOPE_SYSTEM);
            }
        }
        // next iteration's LDS writes fenced by S0/S1 per wave
    }
}

extern "C" void kernel_launch(void* const* d_in, const int* in_sizes, int n_in,
                              void* d_out, int out_size, void* d_ws, size_t ws_size,
                              hipStream_t stream) {
    const float* x  = (const float*)d_in[0];
    const float* Wx = (const float*)d_in[1];
    const float* bx = (const float*)d_in[2];
    const float* Wh = (const float*)d_in[3];
    const float* bh = (const float*)d_in[4];
    float* out = (float*)d_out;

    // workspace: EXACT R2 layout (proven): x_bf16 | ys_bf16 [2][B][T][512] | flags[128]
    unsigned short* xb = (unsigned short*)d_ws;
    unsigned short* ys = xb + SEQELEMS;
    int* flags = (int*)(ys + 2 * SEQELEMS);
    // flags poisoned to 0xAAAAAAAA (<0) by harness; producers store t >= 0,
    // consumers wait for >= t, so poison correctly reads as "not ready".

    int n4 = (int)(SEQELEMS / 4);
    cvt_bf16_kernel<<<dim3((n4 + 255) / 256), dim3(256), 0, stream>>>(x, xb, n4);

    void* args[] = { (void*)&xb, (void*)&ys, (void*)&flags, (void*)&Wx, (void*)&bx,
                     (void*)&Wh, (void*)&bh, (void*)&out };
    hipLaunchCooperativeKernel((void*)lstm_v5, dim3(128), dim3(512), args, 0, stream);
}